// Round 14
// baseline (30.207 us; speedup 1.0000x reference)
//
#include <hip/hip_runtime.h>

// MPS batched contraction via SITE PAIRING (R9/R11/R13-verified):
// G_P[l][pq][d] = Σ_m A_{2P}[l,p,m] A_{2P+1}[m,q,d],  xx[pq] = x_p * y_q,
// left'' = G_P(xx) left.  32 pairs, K=128 each, 32x32x16 f16 MFMA:
//   A-op (G): row d = lane&31, k = 8*(lane>>5) + e
//   B-op (U): col b = lane&31, same k;  C/D: col = lane&31,
//   row l = (reg&3) + 8*(reg>>2) + 4*(lane>>5)
// G-frag kf = pq*2+lh encodes l = 16*lh + (e&3) + 8*(e>>2) + 4*h =>
//   U_frag(kf) = f16(left[e + 8*lh]) * xx[pq]  -- SAME LANE.
//
// R14: HYBRID G delivery. R13's largest wall = LDS pipe (8 waves x 8KB/pair
// ~ 10.2us/CU); the vector-memory pipe is idle and G (256KB) is L2-hot.
// Split per pair: frags kf0-3 from LDS (global_load_lds staged, dbuf),
// frags kf4-7 straight from global, PREFETCHED one pair ahead into 16 VGPRs
// (covers L2 latency under the 8-MFMA chain). LDS wall ~5.1us, global path
// ~5us in parallel. Chunks of 4 pairs -> 8 barriers (was 16). Prep kernel
// 512-thread (dot phase split 2 ways, 1-pass packing).

typedef _Float16 half8 __attribute__((ext_vector_type(8)));
typedef _Float16 half4 __attribute__((ext_vector_type(4)));
typedef float floatx16 __attribute__((ext_vector_type(16)));
typedef float f32x4 __attribute__((ext_vector_type(4)));

#define NPAIRS 32
#define GCHH 8192       // halfs per chunk: 4 pairs * 4 LDS-frags * 512 = 16KB
#define XSTRIDE 129     // padded half4 units per quad line

// ---------------- prep: pair products + fragment packing (512 thr) --------
__global__ void mps_prep_pair(const float* __restrict__ A, _Float16* __restrict__ Gf) {
    __shared__ float sA0[2048], sA1[2048], sG[4096];
    const int P = blockIdx.x, tid = threadIdx.x;      // 512 threads
    const float* a0p = A + (size_t)(2 * P) * 2048;
    const float* a1p = A + (size_t)(2 * P + 1) * 2048;
#pragma unroll
    for (int i = 0; i < 4; ++i) {
        sA0[tid + 512 * i] = a0p[tid + 512 * i];
        sA1[tid + 512 * i] = a1p[tid + 512 * i];
    }
    __syncthreads();
    {   // item = (l, pq, dh16); 2 threads/item, 8 dd each; dot over m=32
        const int item = tid >> 1;
        const int l = item >> 3, pq = (item >> 1) & 3, dh16 = (item & 1) * 16;
        const int ddb = (tid & 1) * 8;
        const int p = pq >> 1, q = pq & 1;
        float accv[8];
#pragma unroll
        for (int dd = 0; dd < 8; ++dd) accv[dd] = 0.f;
        for (int m = 0; m < 32; ++m) {
            const float av = sA0[l * 64 + p * 32 + m];
            const float* bp = &sA1[m * 64 + q * 32 + dh16 + ddb];
#pragma unroll
            for (int dd = 0; dd < 8; ++dd) accv[dd] += av * bp[dd];
        }
#pragma unroll
        for (int dd = 0; dd < 8; ++dd) sG[l * 128 + pq * 32 + dh16 + ddb + dd] = accv[dd];
    }
    __syncthreads();
    // pack: kf = tid>>6 (0..7), single pass
    const int lane = tid & 63;
    const int h    = lane >> 5;
    const int d    = lane & 31;
    const int kf   = tid >> 6;
    const int pq   = kf >> 1, lh = kf & 1;
    half8 v;
#pragma unroll
    for (int e = 0; e < 8; ++e) {
        const int l = 16 * lh + (e & 3) + 8 * (e >> 2) + 4 * h;
        v[e] = (_Float16)sG[l * 128 + pq * 32 + d];
    }
    reinterpret_cast<half8*>(Gf)[((size_t)P * 8 + kf) * 64 + lane] = v;
}

// ---------------- main kernel ----------------
#define MF32(A_, B_, C_) __builtin_amdgcn_mfma_f32_32x32x16_f16(A_, B_, C_, 0, 0, 0)

// Stage chunk C's LDS half (4 pairs x frags kf0-3, 16 recs of 1KB) into BUF.
#define STAGEG(C, BUF)                                                        \
    {                                                                         \
        _Pragma("unroll")                                                     \
        for (int r_ = 0; r_ < 4; ++r_) {                                      \
            const int rec_ = r_ * 4 + wid;                                    \
            const int pl_ = rec_ >> 2, kf_ = rec_ & 3;                        \
            const _Float16* g_ = Gf + ((((size_t)(C) * 4 + pl_) * 8 + kf_) * 64 + lane) * 8; \
            __builtin_amdgcn_global_load_lds(                                 \
                (const __attribute__((address_space(1))) void*)g_,            \
                (__attribute__((address_space(3))) void*)&smG[(BUF) * GCHH + rec_ * 512], \
                16, 0, 0);                                                    \
        }                                                                     \
    }

// One pair. GP = this pair's global frags (kf4-7) already in registers;
// GN receives next pair's. LDS frags kf0-3 read JIT. 8-MFMA in-place chain.
#define PAIRDO(BUF, LP, P, GP, GN)                                            \
    {                                                                         \
        const half4 xq_ = smX[(P) * XSTRIDE + r];                             \
        const _Float16 w00_ = xq_[0] * xq_[2];                                \
        const _Float16 w01_ = xq_[0] * xq_[3];                                \
        const _Float16 w10_ = xq_[1] * xq_[2];                                \
        const _Float16 w11_ = xq_[1] * xq_[3];                                \
        half8 GL_[4];                                                         \
        _Pragma("unroll")                                                     \
        for (int f_ = 0; f_ < 4; ++f_)                                        \
            GL_[f_] = *(const half8*)&smG[(BUF) * GCHH + (((LP) * 4 + f_) * 64 + lane) * 8]; \
        _Pragma("unroll")                                                     \
        for (int f_ = 0; f_ < 4; ++f_)                                        \
            GN[f_] = gfp[((((P) + 1) & 31) * 8 + 4 + f_) * 64 + lane];        \
        half8 FA0_, FA1_;                                                     \
        _Pragma("unroll")                                                     \
        for (int i_ = 0; i_ < 8; ++i_) {                                      \
            FA0_[i_] = (_Float16)acc[i_];                                     \
            FA1_[i_] = (_Float16)acc[8 + i_];                                 \
        }                                                                     \
        floatx16 t_;                                                          \
        t_ = MF32(GL_[0], FA0_ * w00_, zv);                                   \
        t_ = MF32(GL_[1], FA1_ * w00_, t_);                                   \
        t_ = MF32(GL_[2], FA0_ * w01_, t_);                                   \
        t_ = MF32(GL_[3], FA1_ * w01_, t_);                                   \
        t_ = MF32(GP[0], FA0_ * w10_, t_);                                    \
        t_ = MF32(GP[1], FA1_ * w10_, t_);                                    \
        t_ = MF32(GP[2], FA0_ * w11_, t_);                                    \
        t_ = MF32(GP[3], FA1_ * w11_, t_);                                    \
        acc = t_;                                                             \
    }

// One 4-pair chunk: stage next chunk's LDS half up front, compute, barrier.
#define CHUNK(C, BUF)                                                         \
    {                                                                         \
        if ((C) < 7) STAGEG((C) + 1, 1 - (BUF));                              \
        PAIRDO(BUF, 0, 4 * (C) + 0, Ga, Gb)                                   \
        PAIRDO(BUF, 1, 4 * (C) + 1, Gb, Ga)                                   \
        PAIRDO(BUF, 2, 4 * (C) + 2, Ga, Gb)                                   \
        PAIRDO(BUF, 3, 4 * (C) + 3, Gb, Ga)                                   \
        __syncthreads();                                                      \
    }

__global__ __launch_bounds__(256, 2) void mps_main(const float* __restrict__ x,
                                                   const _Float16* __restrict__ Gf,
                                                   float* __restrict__ out) {
    __shared__ __align__(16) _Float16 smG[2 * GCHH];      // 32 KB
    __shared__ __align__(8)  half4    smX[32 * XSTRIDE];  // 33 KB, [quad][row]

    const int tid  = threadIdx.x;
    const int lane = tid & 63;
    const int wid  = tid >> 6;                 // 0..3
    const int brow = blockIdx.x * 128;         // block's first batch row
    const int col  = lane & 31;
    const int r    = wid * 32 + col;           // this wave's row within block

    const half8* gfp = reinterpret_cast<const half8*>(Gf);

    STAGEG(0, 0);

    // x -> LDS f16 transposed [quad][row]: coalesced f32x4 global reads.
#pragma unroll
    for (int i = 0; i < 16; ++i) {
        const int j   = i * 256 + tid;         // 0..4095
        const int row = j >> 5, q = j & 31;
        const f32x4 v = *(const f32x4*)(x + (size_t)(brow + row) * 128 + 4 * q);
        half4 hv;
        hv[0] = (_Float16)v[0]; hv[1] = (_Float16)v[1];
        hv[2] = (_Float16)v[2]; hv[3] = (_Float16)v[3];
        smX[q * XSTRIDE + row] = hv;
    }

    floatx16 zv;
#pragma unroll
    for (int i = 0; i < 16; ++i) zv[i] = 0.f;

    // acc = left[l], l = (reg&3) + 8*(reg>>2) + 4*(lane>>5)
    floatx16 acc;
#pragma unroll
    for (int i = 0; i < 16; ++i) acc[i] = 0.f;
    if (lane < 32) acc[0] = 1.f;               // left0 = e0

    // prefetch pair 0's global frags (kf4-7)
    half8 Ga[4], Gb[4];
#pragma unroll
    for (int f = 0; f < 4; ++f) Ga[f] = gfp[(0 * 8 + 4 + f) * 64 + lane];

    __syncthreads();                            // x in LDS + G chunk 0 ready

    CHUNK(0, 0)  CHUNK(1, 1)  CHUNK(2, 0)  CHUNK(3, 1)
    CHUNK(4, 0)  CHUNK(5, 1)  CHUNK(6, 0)  CHUNK(7, 1)

    // out[b] = left_final[l=0]: reg 0, h=0 -> lanes 0..31
    if (lane < 32) out[brow + wid * 32 + lane] = acc[0];
}

extern "C" void kernel_launch(void* const* d_in, const int* in_sizes, int n_in,
                              void* d_out, int out_size, void* d_ws, size_t ws_size,
                              hipStream_t stream) {
    const float* x = (const float*)d_in[0];   // [65536][64][2] f32
    const float* A = (const float*)d_in[1];   // [64][32][2][32] f32
    float* outp = (float*)d_out;              // [65536] f32
    _Float16* Gf = (_Float16*)d_ws;           // 256 KB pair-fragment fp16

    hipLaunchKernelGGL(mps_prep_pair, dim3(NPAIRS), dim3(512), 0, stream, A, Gf);
    hipLaunchKernelGGL(mps_main, dim3(65536 / 128), dim3(256), 0, stream, x, Gf, outp);
}